// Round 1
// baseline (205.512 us; speedup 1.0000x reference)
//
#include <hip/hip_runtime.h>
#include <math.h>

// ---------------------------------------------------------------------------
// RopeAttentionModel reduced-form implementation.
//
// Key algebra: x[s,:] = c_s * ones(HID)  (c_s = float(input_ids[s]))
//   q[s] = c_s * Sq (colsum Wq), k[s] = c_s * Sk, v[s] = c_s * Sv
//   RoPE => scores[s,hg,k] = c_s*c_k * D[hg, pos_s-pos_k] / sqrt(128)
//   D[hg,d] = sum_{j<64} P[hg,j]*cos(d*f_j) - Q[hg,j]*sin(d*f_j)
//   attn out per (s,hg) = alpha[s,hg] * Sv[h]   (scalar alpha!)
//   final = A[S,32] @ M[32,4096],  M[hg,:] = sum_d Sv[h,d]*Wo[hg*128+d,:]
// ---------------------------------------------------------------------------

#define HID 4096
#define NQH 32
#define NKVH 8
#define HD 128

// ---- column sums of a [rows x cols] f32 matrix (atomic partial chunks) ----
__global__ void k_colsum(const float* __restrict__ W, float* __restrict__ S,
                         int rows, int cols, int rpc) {
    int cvec = blockIdx.x * 256 + threadIdx.x;          // float4 index
    int r0 = blockIdx.y * rpc;
    float4 acc = make_float4(0.f, 0.f, 0.f, 0.f);
    for (int r = r0; r < r0 + rpc; ++r) {
        float4 w = reinterpret_cast<const float4*>(W + (size_t)r * cols)[cvec];
        acc.x += w.x; acc.y += w.y; acc.z += w.z; acc.w += w.w;
    }
    int c = cvec * 4;
    atomicAdd(&S[c + 0], acc.x);
    atomicAdd(&S[c + 1], acc.y);
    atomicAdd(&S[c + 2], acc.z);
    atomicAdd(&S[c + 3], acc.w);
}

// ---- P/Q tables (f64), 32 heads x 64 rotation planes ----
__global__ void k_pq(const float* __restrict__ Sq, const float* __restrict__ Sk,
                     double* __restrict__ P, double* __restrict__ Q) {
    int e = blockIdx.x * 256 + threadIdx.x;   // 0..2047
    if (e >= NQH * 64) return;
    int hg = e >> 6, d = e & 63, h = hg >> 2;
    double a1 = Sq[hg * HD + d], a2 = Sq[hg * HD + d + 64];
    double b1 = Sk[h * HD + d],  b2 = Sk[h * HD + d + 64];
    P[e] = a1 * b1 + a2 * b2;
    Q[e] = a2 * b1 - a1 * b2;
}

// ---- D table: [32][S] in f64 accumulation ----
__global__ void k_dtab(const double* __restrict__ P, const double* __restrict__ Q,
                       float* __restrict__ D, int S) {
    __shared__ double p[64], q[64], f[64];
    int hg = blockIdx.y;
    int tid = threadIdx.x;
    if (tid < 64) {
        p[tid] = P[hg * 64 + tid];
        q[tid] = Q[hg * 64 + tid];
        // match reference's f32 inv_freq, then use exactly in f64
        f[tid] = (double)(float)(1.0 / pow(10000.0, (double)tid / 64.0));
    }
    __syncthreads();
    int dlt = blockIdx.x * 256 + tid;
    if (dlt >= S) return;
    double acc = 0.0;
    for (int d = 0; d < 64; ++d) {
        double sv, cv;
        sincos((double)dlt * f[d], &sv, &cv);
        acc += p[d] * cv - q[d] * sv;
    }
    D[(size_t)hg * S + dlt] = (float)acc;
}

// ---- alpha[s][hg]: one wave per (s,hg), two-pass softmax ----
__global__ void k_alpha(const int* __restrict__ ids, const int* __restrict__ pos,
                        const float* __restrict__ D, float* __restrict__ A, int S) {
    int w = blockIdx.x * 4 + (threadIdx.x >> 6);   // wave id in [0, S*32)
    int lane = threadIdx.x & 63;
    int s = w >> 5, hg = w & 31;
    if (s >= S) return;
    float cs = (float)ids[s];
    float beta = cs * 0.08838834764831845f;        // 1/sqrt(128)
    int ps = pos[s];
    const float* Drow = D + (size_t)hg * S;

    float m = -1e30f;
    for (int k = lane; k <= s; k += 64) {
        int dlt = ps - pos[k];
        dlt = dlt < 0 ? 0 : (dlt > S - 1 ? S - 1 : dlt);
        float z = beta * (float)ids[k] * Drow[dlt];
        m = fmaxf(m, z);
    }
    for (int o = 32; o; o >>= 1) m = fmaxf(m, __shfl_xor(m, o));

    float se = 0.f, sec = 0.f;
    for (int k = lane; k <= s; k += 64) {
        int dlt = ps - pos[k];
        dlt = dlt < 0 ? 0 : (dlt > S - 1 ? S - 1 : dlt);
        float ck = (float)ids[k];
        float z = beta * ck * Drow[dlt];
        float e = __expf(z - m);
        se += e; sec += e * ck;
    }
    for (int o = 32; o; o >>= 1) { se += __shfl_xor(se, o); sec += __shfl_xor(sec, o); }
    if (lane == 0) A[(size_t)s * NQH + hg] = sec / se;
}

// ---- M[32][4096] = per-head Sv . Wo block rows ----
__global__ void k_m(const float* __restrict__ Sv, const float* __restrict__ Wo,
                    float* __restrict__ M) {
    __shared__ float sv[HD];
    int hg = blockIdx.y, h = hg >> 2;
    int tid = threadIdx.x;
    if (tid < HD) sv[tid] = Sv[h * HD + tid];
    __syncthreads();
    int i = blockIdx.x * 256 + tid;
    float acc = 0.f;
#pragma unroll 8
    for (int d = 0; d < HD; ++d)
        acc += sv[d] * Wo[(size_t)(hg * HD + d) * HID + i];
    M[(size_t)hg * HID + i] = acc;
}

// ---- final = A @ M, tiled 16 rows x 256 cols per block ----
__global__ void k_out(const float* __restrict__ A, const float* __restrict__ M,
                      float* __restrict__ out, int S) {
    __shared__ float a[512];                        // 16 rows x 32 heads
    int tid = threadIdx.x;
    int s0 = blockIdx.y * 16;
    a[tid] = A[(size_t)s0 * NQH + tid];
    a[tid + 256] = A[(size_t)s0 * NQH + tid + 256];
    __syncthreads();
    int i = blockIdx.x * 256 + tid;
    float acc[16];
#pragma unroll
    for (int r = 0; r < 16; ++r) acc[r] = 0.f;
    for (int hg = 0; hg < NQH; ++hg) {
        float mv = M[(size_t)hg * HID + i];
#pragma unroll
        for (int r = 0; r < 16; ++r) acc[r] += a[r * NQH + hg] * mv;
    }
#pragma unroll
    for (int r = 0; r < 16; ++r)
        out[(size_t)(s0 + r) * HID + i] = acc[r];
}

extern "C" void kernel_launch(void* const* d_in, const int* in_sizes, int n_in,
                              void* d_out, int out_size, void* d_ws, size_t ws_size,
                              hipStream_t stream) {
    const int*   ids = (const int*)d_in[0];
    const int*   pos = (const int*)d_in[1];
    const float* Wq  = (const float*)d_in[2];
    const float* Wk  = (const float*)d_in[3];
    const float* Wv  = (const float*)d_in[4];
    const float* Wo  = (const float*)d_in[5];
    float* out = (float*)d_out;
    const int S = in_sizes[0];                      // B=1

    float* ws = (float*)d_ws;
    float* Sq = ws;                    // 4096
    float* Sk = Sq + HID;              // 1024
    float* Sv = Sk + NKVH * HD;        // 1024
    float* D  = Sv + NKVH * HD;        // 32*S
    float* M  = D + (size_t)NQH * S;   // 32*4096
    float* A  = M + (size_t)NQH * HID; // S*32
    double* P = (double*)(A + (size_t)S * NQH);     // 2048 doubles
    double* Q = P + NQH * 64;

    // zero the atomic-accumulated column sums
    hipMemsetAsync(ws, 0, (HID + 2 * NKVH * HD) * sizeof(float), stream);

    k_colsum<<<dim3(4, 128), 256, 0, stream>>>(Wq, Sq, HID, NQH * HD, 32);
    k_colsum<<<dim3(1, 128), 256, 0, stream>>>(Wk, Sk, HID, NKVH * HD, 32);
    k_colsum<<<dim3(1, 128), 256, 0, stream>>>(Wv, Sv, HID, NKVH * HD, 32);

    k_pq<<<8, 256, 0, stream>>>(Sq, Sk, P, Q);
    k_dtab<<<dim3((S + 255) / 256, NQH), 256, 0, stream>>>(P, Q, D, S);
    k_m<<<dim3(HID / 256, NQH), 256, 0, stream>>>(Sv, Wo, M);
    k_alpha<<<S * 8, 256, 0, stream>>>(ids, pos, D, A, S);
    k_out<<<dim3(HID / 256, S / 16), 256, 0, stream>>>(A, M, out, S);
}

// Round 2
// 147.217 us; speedup vs baseline: 1.3960x; 1.3960x over previous
//
#include <hip/hip_runtime.h>
#include <math.h>

// ---------------------------------------------------------------------------
// RopeAttentionModel reduced form:
//   x[s,:] = c_s * ones(HID)  =>  q/k/v are rank-1: c_s * colsum(W)
//   scores[s,hg,k] = c_s*c_k * D[hg, s-k] / sqrt(128)
//   D[hg,d] = sum_j P[hg,j]*cos(d*f_j) - Q[hg,j]*sin(d*f_j)   (f64)
//   attn out scalar alpha[s,hg] = softmax-weighted mean of c_k
//   final = A[S,32] @ M[32,4096],  M[hg,:] = Sv[h] . Wo[hg*128:+128, :]
// ---------------------------------------------------------------------------

#define HID 4096
#define NQH 32
#define NKVH 8
#define HD 128
#define RSQRT_HD 0.08838834764831845f
#define SQRT_HD  11.313708498984761f

// ---- fused column sums of Wq/Wk/Wv (atomic partial chunks) ----
__global__ void k_colsum3(const float* __restrict__ Wq, const float* __restrict__ Wk,
                          const float* __restrict__ Wv, float* __restrict__ Sq,
                          float* __restrict__ Sk, float* __restrict__ Sv) {
    const float* W; float* Sd; int cols;
    if (blockIdx.z == 0)      { W = Wq; Sd = Sq; cols = NQH * HD; }
    else if (blockIdx.z == 1) { W = Wk; Sd = Sk; cols = NKVH * HD; }
    else                      { W = Wv; Sd = Sv; cols = NKVH * HD; }
    int cvec = blockIdx.x * 256 + threadIdx.x;
    if (cvec * 4 >= cols) return;
    int r0 = blockIdx.y * 32;
    float4 acc = make_float4(0.f, 0.f, 0.f, 0.f);
    for (int r = r0; r < r0 + 32; ++r) {
        float4 w = reinterpret_cast<const float4*>(W + (size_t)r * cols)[cvec];
        acc.x += w.x; acc.y += w.y; acc.z += w.z; acc.w += w.w;
    }
    int c = cvec * 4;
    atomicAdd(&Sd[c + 0], acc.x);
    atomicAdd(&Sd[c + 1], acc.y);
    atomicAdd(&Sd[c + 2], acc.z);
    atomicAdd(&Sd[c + 3], acc.w);
}

// ---- shared trig table Tc/Ts[j][dlt] (f64) + cp[] = ids/sqrt(128) ----
__global__ void k_trig(const int* __restrict__ ids, float* __restrict__ cp,
                       double* __restrict__ Tc, double* __restrict__ Ts, int S) {
    int dlt = blockIdx.x * 256 + threadIdx.x;
    int j = blockIdx.y;
    double f = (double)(float)(1.0 / pow(10000.0, (double)j / 64.0));
    double sv, cv;
    sincos((double)dlt * f, &sv, &cv);
    Tc[(size_t)j * S + dlt] = cv;
    Ts[(size_t)j * S + dlt] = sv;
    if (j == 0) cp[dlt] = (float)ids[dlt] * RSQRT_HD;
}

// ---- D table: [32][S], f64 accumulation over the shared trig table ----
__global__ void k_dtab(const float* __restrict__ Sq, const float* __restrict__ Sk,
                       const double* __restrict__ Tc, const double* __restrict__ Ts,
                       float* __restrict__ D, int S) {
    __shared__ double p[64], q[64];
    int hg = blockIdx.y, h = hg >> 2;
    int tid = threadIdx.x;
    if (tid < 64) {
        double a1 = Sq[hg * HD + tid], a2 = Sq[hg * HD + tid + 64];
        double b1 = Sk[h * HD + tid],  b2 = Sk[h * HD + tid + 64];
        p[tid] = a1 * b1 + a2 * b2;
        q[tid] = a2 * b1 - a1 * b2;
    }
    __syncthreads();
    int dlt = blockIdx.x * 256 + tid;
    double acc = 0.0;
    for (int j = 0; j < 64; ++j)
        acc += p[j] * Tc[(size_t)j * S + dlt] - q[j] * Ts[(size_t)j * S + dlt];
    D[(size_t)hg * S + dlt] = (float)acc;
}

// ---- alpha[s][hg]: one wave per (s,hg), single-pass online softmax ----
__global__ __launch_bounds__(256) void k_alpha(
        const int* __restrict__ ids, const float* __restrict__ cp,
        const float* __restrict__ D, float* __restrict__ A, int S) {
    int w = blockIdx.x * 4 + (threadIdx.x >> 6);
    int lane = threadIdx.x & 63;
    int s = S - 1 - (w >> 5);              // long rows dispatched first
    int hg = w & 31;
    float cs = (float)ids[s];
    const float* Drow = D + (size_t)hg * S;
    const float* cps = cp + s;             // cps[-dlt] = cp[s-dlt] = cp[k]

    float m = -INFINITY, se = 0.f, sp = 0.f;
    int n = s + 1;
    int nFull = n >> 8;                    // full 256-element chunks
    for (int it = 0; it < nFull; ++it) {
        int d0 = it * 256 + lane * 4;
        float4 dv = *reinterpret_cast<const float4*>(Drow + d0);
        float c0 = cps[-(d0 + 0)], c1 = cps[-(d0 + 1)];
        float c2 = cps[-(d0 + 2)], c3 = cps[-(d0 + 3)];
        float z0 = cs * (c0 * dv.x), z1 = cs * (c1 * dv.y);
        float z2 = cs * (c2 * dv.z), z3 = cs * (c3 * dv.w);
        float zc = fmaxf(fmaxf(z0, z1), fmaxf(z2, z3));
        float r = __expf(fminf(m - zc, 0.f));   // branchless deferred rescale
        se *= r; sp *= r; m = fmaxf(m, zc);
        float e0 = __expf(z0 - m), e1 = __expf(z1 - m);
        float e2 = __expf(z2 - m), e3 = __expf(z3 - m);
        se += (e0 + e1) + (e2 + e3);
        sp += e0 * c0 + e1 * c1 + e2 * c2 + e3 * c3;
    }
    if (n & 255) {                          // masked tail chunk
        int d0 = nFull * 256 + lane * 4;
        float4 dv = *reinterpret_cast<const float4*>(Drow + d0); // padded OOB ok
        float c0 = cps[-(d0 + 0)], c1 = cps[-(d0 + 1)];
        float c2 = cps[-(d0 + 2)], c3 = cps[-(d0 + 3)];
        float z0 = (d0 + 0 < n) ? cs * (c0 * dv.x) : -INFINITY;
        float z1 = (d0 + 1 < n) ? cs * (c1 * dv.y) : -INFINITY;
        float z2 = (d0 + 2 < n) ? cs * (c2 * dv.z) : -INFINITY;
        float z3 = (d0 + 3 < n) ? cs * (c3 * dv.w) : -INFINITY;
        float zc = fmaxf(fmaxf(z0, z1), fmaxf(z2, z3));
        float r = __expf(fminf(m - zc, 0.f));   // min kills -inf-(-inf)=NaN
        se *= r; sp *= r; m = fmaxf(m, zc);
        float mm = fmaxf(m, -1e30f);            // keep finite for lanes w/o data
        float e0 = __expf(z0 - mm), e1 = __expf(z1 - mm);
        float e2 = __expf(z2 - mm), e3 = __expf(z3 - mm);
        se += (e0 + e1) + (e2 + e3);
        sp += e0 * c0 + e1 * c1 + e2 * c2 + e3 * c3;
    }
    // cross-lane merge of (m, se, sp)
    for (int o = 32; o; o >>= 1) {
        float mo = __shfl_xor(m, o);
        float so = __shfl_xor(se, o);
        float po = __shfl_xor(sp, o);
        float M = fmaxf(m, mo);
        float e1 = __expf(fminf(m - M, 0.f));
        float e2 = __expf(fminf(mo - M, 0.f));
        se = se * e1 + so * e2;
        sp = sp * e1 + po * e2;
        m = M;
    }
    if (lane == 0) A[(size_t)s * NQH + hg] = SQRT_HD * sp / se;
}

// ---- M[32][4096] = Sv[h] . Wo rows, float4 + d-split atomics ----
__global__ void k_m(const float* __restrict__ Sv, const float* __restrict__ Wo,
                    float* __restrict__ M) {
    __shared__ float sv[32];
    int hg = blockIdx.y, h = hg >> 2;
    int d0 = blockIdx.z * 32;
    if (threadIdx.x < 32) sv[threadIdx.x] = Sv[h * HD + d0 + threadIdx.x];
    __syncthreads();
    int i4 = blockIdx.x * 256 + threadIdx.x;   // float4 column index
    float4 acc = make_float4(0.f, 0.f, 0.f, 0.f);
    for (int dd = 0; dd < 32; ++dd) {
        float4 w = reinterpret_cast<const float4*>(
            Wo + (size_t)(hg * HD + d0 + dd) * HID)[i4];
        float s = sv[dd];
        acc.x += s * w.x; acc.y += s * w.y; acc.z += s * w.z; acc.w += s * w.w;
    }
    int c = i4 * 4;
    atomicAdd(&M[(size_t)hg * HID + c + 0], acc.x);
    atomicAdd(&M[(size_t)hg * HID + c + 1], acc.y);
    atomicAdd(&M[(size_t)hg * HID + c + 2], acc.z);
    atomicAdd(&M[(size_t)hg * HID + c + 3], acc.w);
}

// ---- final = A @ M, tiled 16 rows x 256 cols per block ----
__global__ void k_out(const float* __restrict__ A, const float* __restrict__ M,
                      float* __restrict__ out, int S) {
    __shared__ float a[512];
    int tid = threadIdx.x;
    int s0 = blockIdx.y * 16;
    a[tid] = A[(size_t)s0 * NQH + tid];
    a[tid + 256] = A[(size_t)s0 * NQH + tid + 256];
    __syncthreads();
    int i = blockIdx.x * 256 + tid;
    float acc[16];
#pragma unroll
    for (int r = 0; r < 16; ++r) acc[r] = 0.f;
    for (int hg = 0; hg < NQH; ++hg) {
        float mv = M[(size_t)hg * HID + i];
#pragma unroll
        for (int r = 0; r < 16; ++r) acc[r] += a[r * NQH + hg] * mv;
    }
#pragma unroll
    for (int r = 0; r < 16; ++r)
        out[(size_t)(s0 + r) * HID + i] = acc[r];
}

extern "C" void kernel_launch(void* const* d_in, const int* in_sizes, int n_in,
                              void* d_out, int out_size, void* d_ws, size_t ws_size,
                              hipStream_t stream) {
    const int*   ids = (const int*)d_in[0];
    const float* Wq  = (const float*)d_in[2];
    const float* Wk  = (const float*)d_in[3];
    const float* Wv  = (const float*)d_in[4];
    const float* Wo  = (const float*)d_in[5];
    float* out = (float*)d_out;
    const int S = in_sizes[0];                      // B=1, S=2048

    // ws layout (floats unless noted):
    //   Sq[4096] Sk[1024] Sv[1024] D[32*S] cp[S] A[32*S]
    //   then U: Tc[64*S f64] Ts[64*S f64]; M[32*4096] aliases U (k_m after k_dtab)
    float* ws = (float*)d_ws;
    float* Sq = ws;
    float* Sk = Sq + HID;
    float* Sv = Sk + NKVH * HD;
    float* D  = Sv + NKVH * HD;                 // OOB float4 pad reads land in cp/A
    float* cp = D + (size_t)NQH * S;            // OOB-before reads land in D
    float* A  = cp + S;
    double* Tc = (double*)(A + (size_t)NQH * S);
    double* Ts = Tc + (size_t)64 * S;
    float* M  = (float*)Tc;                     // reuse: M written after Tc/Ts consumed

    hipMemsetAsync(Sq, 0, (HID + 2 * NKVH * HD) * sizeof(float), stream);
    k_colsum3<<<dim3(4, 128, 3), 256, 0, stream>>>(Wq, Wk, Wv, Sq, Sk, Sv);
    k_trig<<<dim3(S / 256, 64), 256, 0, stream>>>(ids, cp, Tc, Ts, S);
    k_dtab<<<dim3(S / 256, NQH), 256, 0, stream>>>(Sq, Sk, Tc, Ts, D, S);
    hipMemsetAsync(M, 0, (size_t)NQH * HID * sizeof(float), stream);
    k_m<<<dim3(HID / 1024, NQH, 4), 256, 0, stream>>>(Sv, Wo, M);
    k_alpha<<<S * 8, 256, 0, stream>>>(ids, cp, D, A, S);
    k_out<<<dim3(HID / 256, S / 16), 256, 0, stream>>>(A, M, out, S);
}